// Round 5
// baseline (26002.194 us; speedup 1.0000x reference)
//
#include <hip/hip_runtime.h>
#include <cmath>

#define T_STEPS 16384
#define NH 361
#define NIN 489
#define NRULE 128

typedef _Float16 half8 __attribute__((ext_vector_type(8)));
typedef _Float16 h2_t __attribute__((ext_vector_type(2)));
typedef float f32x4 __attribute__((ext_vector_type(4)));

static constexpr double PI_D = 3.14159265358979323846;

// ---------------------------------------------------------------------------
// k0: one-time prep: transpose W2 = w_ih[:,128:] into w2t[j][i], and fold
//     A[i] = w_ih[i,:128] @ w_rule,  C[i] = w_ih[i,:128] @ b_rule + b_ih + b_hh
// ---------------------------------------------------------------------------
__global__ void k0_prep(const float* __restrict__ w_ih, const float* __restrict__ w_rule,
                        const float* __restrict__ b_rule, const float* __restrict__ b_ih,
                        const float* __restrict__ b_hh,
                        float* __restrict__ Av, float* __restrict__ Cv,
                        float* __restrict__ w2t) {
  int idx = blockIdx.x * 256 + threadIdx.x;
  if (idx < NH * NH) {
    int i = idx % NH;       // output row of w_ih
    int j = idx / NH;       // angle-grid column
    w2t[idx] = w_ih[i * NIN + NRULE + j];   // w2t[j*NH + i]
  }
  if (idx < NH) {
    float a = 0.f, c = 0.f;
    for (int k = 0; k < NRULE; ++k) {
      float w = w_ih[idx * NIN + k];
      a += w * w_rule[k];
      c += w * b_rule[k];
    }
    Av[idx] = a;
    Cv[idx] = c + b_ih[idx] + b_hh[idx];
  }
}

// ---------------------------------------------------------------------------
// k1: xw[t][i] = sum_j w2t[j][i]*vm[t][j] + rule[t]*A[i] + C[i]
// ---------------------------------------------------------------------------
__global__ void k1_xw(const float* __restrict__ angle, const float* __restrict__ rule,
                      const float* __restrict__ Av, const float* __restrict__ Cv,
                      const float* __restrict__ w2t, float* __restrict__ xw,
                      float kappa, float vmS) {
  __shared__ float vm[NH][32];
  __shared__ float srule[32];
  const int tid = threadIdx.x;
  const int t0 = blockIdx.x * 32;
  const float DEG = (float)(PI_D / 180.0);

  for (int idx = tid; idx < NH * 32; idx += 256) {
    int j = idx >> 5;
    int tt = idx & 31;
    float mu = angle[t0 + tt] * DEG;
    float c = __cosf((float)j * DEG - mu);
    vm[j][tt] = vmS * __expf(kappa * (c - 1.f));
  }
  if (tid < 32) srule[tid] = rule[t0 + tid];
  __syncthreads();

  for (int i = tid; i < NH; i += 256) {
    float acc[32];
#pragma unroll
    for (int tt = 0; tt < 32; ++tt) acc[tt] = 0.f;
    for (int j = 0; j < NH; ++j) {
      float wv = w2t[j * NH + i];
#pragma unroll
      for (int tt = 0; tt < 32; ++tt) acc[tt] += wv * vm[j][tt];
    }
    float Ai = Av[i], Ci = Cv[i];
#pragma unroll
    for (int tt = 0; tt < 32; ++tt)
      xw[(t0 + tt) * NH + i] = acc[tt] + srule[tt] * Ai + Ci;
  }
}

// ---------------------------------------------------------------------------
// k2: sequential RNN on the VALU via v_dot2_f32_f16, weights REGISTER-resident.
//   512 threads = 8 waves; amdgpu_waves_per_eu(2,2) pins 2 waves/SIMD so the
//   allocator budget is 256 VGPRs (demand ~202: wt 144 + hc 24 + misc).
//   R0/R2/R4 all silently spilled the weight array (VGPR_Count 84-128 vs
//   demand 140-200) -> ~147 KB/step scratch reload = the real bottleneck.
//   Thread (g = tid>>3, s = tid&7): partials over k in [s*48, s*48+48) for 6
//   rows i = r*64 + g. h chunk: 6 ds_read_b128, reused for 6 rows. S=8
//   reduce on VALU DPP (xor1, xor2, row_shl:4). Lane s==0 finishes rows.
// ---------------------------------------------------------------------------
__device__ __forceinline__ float dot8(half8 a, half8 b, float acc) {
  acc = __builtin_amdgcn_fdot2(__builtin_shufflevector(a, a, 0, 1),
                               __builtin_shufflevector(b, b, 0, 1), acc, false);
  acc = __builtin_amdgcn_fdot2(__builtin_shufflevector(a, a, 2, 3),
                               __builtin_shufflevector(b, b, 2, 3), acc, false);
  acc = __builtin_amdgcn_fdot2(__builtin_shufflevector(a, a, 4, 5),
                               __builtin_shufflevector(b, b, 4, 5), acc, false);
  acc = __builtin_amdgcn_fdot2(__builtin_shufflevector(a, a, 6, 7),
                               __builtin_shufflevector(b, b, 6, 7), acc, false);
  return acc;
}

template <int CTRL>
__device__ __forceinline__ float dpp_add(float x) {
  int m = __builtin_amdgcn_update_dpp(0, __float_as_int(x), CTRL, 0xF, 0xF, true);
  return x + __int_as_float(m);
}

__global__ __launch_bounds__(512)
__attribute__((amdgpu_waves_per_eu(2, 2)))
void k2_rnn(const float* __restrict__ w_hh, const float* __restrict__ xw,
            float* __restrict__ hs) {
  __shared__ __align__(16) _Float16 hbuf[2][384];
  const int tid = threadIdx.x;
  const int g = tid >> 3;        // row group 0..63
  const int s = tid & 7;         // k-split 0..7

  // zero both h buffers (h0 = 0; pad rows 361..383 stay 0 forever)
  for (int idx = tid; idx < 768; idx += 512)
    ((_Float16*)hbuf)[idx] = (_Float16)0.f;

  // Weights: rows i = r*64+g, k in [s*48, s*48+48), f16-packed: 144 VGPRs.
  half8 wt8[36];   // [r*6 + c]
#pragma unroll
  for (int r = 0; r < 6; ++r) {
    const int i = r * 64 + g;
#pragma unroll
    for (int c = 0; c < 6; ++c) {
      half8 v;
#pragma unroll
      for (int e = 0; e < 8; ++e) {
        const int k = s * 48 + c * 8 + e;
        float x = (i < NH && k < NH) ? w_hh[i * NH + k] : 0.f;
        v[e] = (_Float16)x;
      }
      wt8[r * 6 + c] = v;
    }
  }
  // Pin each weight vector as an opaque register value: forbids the compiler
  // from sinking the w_hh loads into the t-loop (reload-per-step).
#pragma unroll
  for (int c = 0; c < 36; ++c) {
    f32x4 tmp = __builtin_bit_cast(f32x4, wt8[c]);
    asm volatile("" : "+v"(tmp));
    wt8[c] = __builtin_bit_cast(half8, tmp);
  }

  float xwv[6];
  if (s == 0) {
#pragma unroll
    for (int r = 0; r < 6; ++r) {
      const int i = r * 64 + g;
      xwv[r] = (i < NH) ? xw[i] : 0.f;
    }
  }
  __syncthreads();

  for (int t = 0; t < T_STEPS; ++t) {
    // h chunk for this thread's k-split: 6 x ds_read_b128, reused for 6 rows
    const _Float16* hb = &hbuf[t & 1][s * 48];
    half8 hc[6];
#pragma unroll
    for (int c = 0; c < 6; ++c) hc[c] = *(const half8*)(hb + c * 8);

    // prefetch next step's xw (s==0 lanes only), hidden under the dot phase
    const int tn = (t + 1 < T_STEPS) ? (t + 1) : t;
    float xwn[6];
    if (s == 0) {
      const float* pn = xw + (size_t)tn * NH;
#pragma unroll
      for (int r = 0; r < 6; ++r) {
        const int i = r * 64 + g;
        xwn[r] = (i < NH) ? pn[i] : 0.f;
      }
    }

    float ps[6] = {0.f, 0.f, 0.f, 0.f, 0.f, 0.f};
#pragma unroll
    for (int c = 0; c < 6; ++c)
#pragma unroll
      for (int r = 0; r < 6; ++r)
        ps[r] = dot8(hc[c], wt8[r * 6 + c], ps[r]);

    // reduce the 8 k-split partials onto lane s==0 of each group (VALU DPP)
#pragma unroll
    for (int r = 0; r < 6; ++r) {
      float v = ps[r];
      v = dpp_add<0xB1>(v);    // quad_perm(1,0,3,2): += lane^1
      v = dpp_add<0x4E>(v);    // quad_perm(2,3,0,1): += lane^2
      v = dpp_add<0x104>(v);   // row_shl:4: lane i += lane i+4
      ps[r] = v;
    }

    if (s == 0) {
      float* orow = hs + (size_t)t * NH;
      _Float16* nb = hbuf[(t + 1) & 1];
#pragma unroll
      for (int r = 0; r < 6; ++r) {
        const int i = r * 64 + g;
        if (i < NH) {
          const float sv = ps[r] + xwv[r];
          const float e = __expf(2.f * sv);
          const float h = 1.f - __fdividef(2.f, e + 1.f);
          orow[i] = h;
          nb[i] = (_Float16)h;
        }
        xwv[r] = xwn[r];
      }
    }
    __syncthreads();
  }
}

// ---------------------------------------------------------------------------
// k3: outcome_pre[t] = w_fc . hs[t] + b_fc   (one wave per timestep)
// ---------------------------------------------------------------------------
__global__ void k3_fc(const float* __restrict__ hs, const float* __restrict__ w_fc,
                      const float* __restrict__ b_fc, float* __restrict__ out0) {
  const int t = blockIdx.x * 4 + (threadIdx.x >> 6);
  const int lane = threadIdx.x & 63;
  const float* hrow = hs + (size_t)t * NH;
  float s = 0.f;
  for (int j = lane; j < NH; j += 64) s += w_fc[j] * hrow[j];
#pragma unroll
  for (int off = 32; off > 0; off >>= 1) s += __shfl_down(s, off, 64);
  if (lane == 0) out0[t] = s + b_fc[0];
}

extern "C" void kernel_launch(void* const* d_in, const int* in_sizes, int n_in,
                              void* d_out, int out_size, void* d_ws, size_t ws_size,
                              hipStream_t stream) {
  const float* angle  = (const float*)d_in[0];
  const float* rule   = (const float*)d_in[1];
  const float* w_rule = (const float*)d_in[2];
  const float* b_rule = (const float*)d_in[3];
  const float* w_ih   = (const float*)d_in[4];
  const float* w_hh   = (const float*)d_in[5];
  const float* b_ih   = (const float*)d_in[6];
  const float* b_hh   = (const float*)d_in[7];
  const float* w_fc   = (const float*)d_in[8];
  const float* b_fc   = (const float*)d_in[9];
  float* out = (float*)d_out;

  // workspace layout (floats): xw[T*NH] | A[NH] | C[NH] | w2t[NH*NH]
  float* xw  = (float*)d_ws;
  float* Av  = xw + (size_t)T_STEPS * NH;
  float* Cv  = Av + NH;
  float* w2t = Cv + NH;

  // S = e^kappa / (2*pi*I0(kappa)) = sqrt(kappa/(2*pi)) / asymptotic_series
  const double kappa = 1.0 / (0.1745 * 0.1745);
  double series = 1.0, term = 1.0;
  for (int k = 1; k < 16; ++k) {
    term *= ((2.0 * k - 1.0) * (2.0 * k - 1.0)) / (8.0 * kappa * (double)k);
    series += term;
  }
  const float vmS = (float)(sqrt(kappa / (2.0 * PI_D)) / series);

  k0_prep<<<(NH * NH + 255) / 256, 256, 0, stream>>>(w_ih, w_rule, b_rule, b_ih, b_hh,
                                                     Av, Cv, w2t);
  k1_xw<<<T_STEPS / 32, 256, 0, stream>>>(angle, rule, Av, Cv, w2t, xw,
                                          (float)kappa, vmS);
  k2_rnn<<<1, 512, 0, stream>>>(w_hh, xw, out + T_STEPS);
  k3_fc<<<T_STEPS / 4, 256, 0, stream>>>(out + T_STEPS, w_fc, b_fc, out);
}

// Round 6
// 24986.804 us; speedup vs baseline: 1.0406x; 1.0406x over previous
//
#include <hip/hip_runtime.h>
#include <cmath>

#define T_STEPS 16384
#define NH 361
#define NIN 489
#define NRULE 128

typedef _Float16 half8 __attribute__((ext_vector_type(8)));
typedef _Float16 h2_t __attribute__((ext_vector_type(2)));

static constexpr double PI_D = 3.14159265358979323846;

// ---------------------------------------------------------------------------
// k0: one-time prep: transpose W2 = w_ih[:,128:] into w2t[j][i], and fold
//     A[i] = w_ih[i,:128] @ w_rule,  C[i] = w_ih[i,:128] @ b_rule + b_ih + b_hh
// ---------------------------------------------------------------------------
__global__ void k0_prep(const float* __restrict__ w_ih, const float* __restrict__ w_rule,
                        const float* __restrict__ b_rule, const float* __restrict__ b_ih,
                        const float* __restrict__ b_hh,
                        float* __restrict__ Av, float* __restrict__ Cv,
                        float* __restrict__ w2t) {
  int idx = blockIdx.x * 256 + threadIdx.x;
  if (idx < NH * NH) {
    int i = idx % NH;       // output row of w_ih
    int j = idx / NH;       // angle-grid column
    w2t[idx] = w_ih[i * NIN + NRULE + j];   // w2t[j*NH + i]
  }
  if (idx < NH) {
    float a = 0.f, c = 0.f;
    for (int k = 0; k < NRULE; ++k) {
      float w = w_ih[idx * NIN + k];
      a += w * w_rule[k];
      c += w * b_rule[k];
    }
    Av[idx] = a;
    Cv[idx] = c + b_ih[idx] + b_hh[idx];
  }
}

// ---------------------------------------------------------------------------
// k1: xw[t][i] = sum_j w2t[j][i]*vm[t][j] + rule[t]*A[i] + C[i]
// ---------------------------------------------------------------------------
__global__ void k1_xw(const float* __restrict__ angle, const float* __restrict__ rule,
                      const float* __restrict__ Av, const float* __restrict__ Cv,
                      const float* __restrict__ w2t, float* __restrict__ xw,
                      float kappa, float vmS) {
  __shared__ float vm[NH][32];
  __shared__ float srule[32];
  const int tid = threadIdx.x;
  const int t0 = blockIdx.x * 32;
  const float DEG = (float)(PI_D / 180.0);

  for (int idx = tid; idx < NH * 32; idx += 256) {
    int j = idx >> 5;
    int tt = idx & 31;
    float mu = angle[t0 + tt] * DEG;
    float c = __cosf((float)j * DEG - mu);
    vm[j][tt] = vmS * __expf(kappa * (c - 1.f));
  }
  if (tid < 32) srule[tid] = rule[t0 + tid];
  __syncthreads();

  for (int i = tid; i < NH; i += 256) {
    float acc[32];
#pragma unroll
    for (int tt = 0; tt < 32; ++tt) acc[tt] = 0.f;
    for (int j = 0; j < NH; ++j) {
      float wv = w2t[j * NH + i];
#pragma unroll
      for (int tt = 0; tt < 32; ++tt) acc[tt] += wv * vm[j][tt];
    }
    float Ai = Av[i], Ci = Cv[i];
#pragma unroll
    for (int tt = 0; tt < 32; ++tt)
      xw[(t0 + tt) * NH + i] = acc[tt] + srule[tt] * Ai + Ci;
  }
}

// ---------------------------------------------------------------------------
// k2: sequential RNN on the VALU via v_dot2_f32_f16, weights register-resident.
//   512 threads = 8 waves. NO __launch_bounds__: instead
//   amdgpu_flat_work_group_size(512,512) + amdgpu_waves_per_eu(2,2) pins the
//   backend to exactly 2 waves/EU (1 block/CU) -> VGPR budget 512/2 = 256.
//   (R0-R5 history: with launch_bounds present, the default occupancy
//   heuristic targeted >=4 waves/EU and capped VGPRs at 128/84, silently
//   spilling the 144-reg weight array to scratch -> ~150 KB/step reload,
//   which was the true bottleneck of every previous round.)
//   Thread (g = tid>>3, s = tid&7): partials over k in [s*48, s*48+48) for 6
//   rows i = r*64 + g. h chunk: 6 ds_read_b128, reused for 6 rows. S=8
//   reduce on VALU DPP (xor1, xor2, row_shl:4). Lane s==0 finishes rows.
// ---------------------------------------------------------------------------
__device__ __forceinline__ float dot8(half8 a, half8 b, float acc) {
  acc = __builtin_amdgcn_fdot2(__builtin_shufflevector(a, a, 0, 1),
                               __builtin_shufflevector(b, b, 0, 1), acc, false);
  acc = __builtin_amdgcn_fdot2(__builtin_shufflevector(a, a, 2, 3),
                               __builtin_shufflevector(b, b, 2, 3), acc, false);
  acc = __builtin_amdgcn_fdot2(__builtin_shufflevector(a, a, 4, 5),
                               __builtin_shufflevector(b, b, 4, 5), acc, false);
  acc = __builtin_amdgcn_fdot2(__builtin_shufflevector(a, a, 6, 7),
                               __builtin_shufflevector(b, b, 6, 7), acc, false);
  return acc;
}

template <int CTRL>
__device__ __forceinline__ float dpp_add(float x) {
  int m = __builtin_amdgcn_update_dpp(0, __float_as_int(x), CTRL, 0xF, 0xF, true);
  return x + __int_as_float(m);
}

__global__
__attribute__((amdgpu_flat_work_group_size(512, 512), amdgpu_waves_per_eu(2, 2)))
void k2_rnn(const float* __restrict__ w_hh, const float* __restrict__ xw,
            float* __restrict__ hs) {
  __shared__ __align__(16) _Float16 hbuf[2][384];
  const int tid = threadIdx.x;
  const int g = tid >> 3;        // row group 0..63
  const int s = tid & 7;         // k-split 0..7

  // zero both h buffers (h0 = 0; pad rows 361..383 stay 0 forever)
  for (int idx = tid; idx < 768; idx += 512)
    ((_Float16*)hbuf)[idx] = (_Float16)0.f;

  // Weights: rows i = r*64+g, k in [s*48, s*48+48), f16-packed: 144 VGPRs.
  half8 wt8[36];   // [r*6 + c]
#pragma unroll
  for (int r = 0; r < 6; ++r) {
    const int i = r * 64 + g;
#pragma unroll
    for (int c = 0; c < 6; ++c) {
      half8 v;
#pragma unroll
      for (int e = 0; e < 8; ++e) {
        const int k = s * 48 + c * 8 + e;
        float x = (i < NH && k < NH) ? w_hh[i * NH + k] : 0.f;
        v[e] = (_Float16)x;
      }
      wt8[r * 6 + c] = v;
    }
  }

  float xwv[6];
  if (s == 0) {
#pragma unroll
    for (int r = 0; r < 6; ++r) {
      const int i = r * 64 + g;
      xwv[r] = (i < NH) ? xw[i] : 0.f;
    }
  }
  __syncthreads();

  for (int t = 0; t < T_STEPS; ++t) {
    // h chunk for this thread's k-split: 6 x ds_read_b128, reused for 6 rows
    const _Float16* hb = &hbuf[t & 1][s * 48];
    half8 hc[6];
#pragma unroll
    for (int c = 0; c < 6; ++c) hc[c] = *(const half8*)(hb + c * 8);

    // prefetch next step's xw (s==0 lanes only), hidden under the dot phase
    const int tn = (t + 1 < T_STEPS) ? (t + 1) : t;
    float xwn[6];
    if (s == 0) {
      const float* pn = xw + (size_t)tn * NH;
#pragma unroll
      for (int r = 0; r < 6; ++r) {
        const int i = r * 64 + g;
        xwn[r] = (i < NH) ? pn[i] : 0.f;
      }
    }

    float ps[6] = {0.f, 0.f, 0.f, 0.f, 0.f, 0.f};
#pragma unroll
    for (int c = 0; c < 6; ++c)
#pragma unroll
      for (int r = 0; r < 6; ++r)
        ps[r] = dot8(hc[c], wt8[r * 6 + c], ps[r]);

    // reduce the 8 k-split partials onto lane s==0 of each group (VALU DPP)
#pragma unroll
    for (int r = 0; r < 6; ++r) {
      float v = ps[r];
      v = dpp_add<0xB1>(v);    // quad_perm(1,0,3,2): += lane^1
      v = dpp_add<0x4E>(v);    // quad_perm(2,3,0,1): += lane^2
      v = dpp_add<0x104>(v);   // row_shl:4: lane i += lane i+4
      ps[r] = v;
    }

    if (s == 0) {
      float* orow = hs + (size_t)t * NH;
      _Float16* nb = hbuf[(t + 1) & 1];
#pragma unroll
      for (int r = 0; r < 6; ++r) {
        const int i = r * 64 + g;
        if (i < NH) {
          const float sv = ps[r] + xwv[r];
          const float e = __expf(2.f * sv);
          const float h = 1.f - __fdividef(2.f, e + 1.f);
          orow[i] = h;
          nb[i] = (_Float16)h;
        }
        xwv[r] = xwn[r];
      }
    }
    __syncthreads();
  }
}

// ---------------------------------------------------------------------------
// k3: outcome_pre[t] = w_fc . hs[t] + b_fc   (one wave per timestep)
// ---------------------------------------------------------------------------
__global__ void k3_fc(const float* __restrict__ hs, const float* __restrict__ w_fc,
                      const float* __restrict__ b_fc, float* __restrict__ out0) {
  const int t = blockIdx.x * 4 + (threadIdx.x >> 6);
  const int lane = threadIdx.x & 63;
  const float* hrow = hs + (size_t)t * NH;
  float s = 0.f;
  for (int j = lane; j < NH; j += 64) s += w_fc[j] * hrow[j];
#pragma unroll
  for (int off = 32; off > 0; off >>= 1) s += __shfl_down(s, off, 64);
  if (lane == 0) out0[t] = s + b_fc[0];
}

extern "C" void kernel_launch(void* const* d_in, const int* in_sizes, int n_in,
                              void* d_out, int out_size, void* d_ws, size_t ws_size,
                              hipStream_t stream) {
  const float* angle  = (const float*)d_in[0];
  const float* rule   = (const float*)d_in[1];
  const float* w_rule = (const float*)d_in[2];
  const float* b_rule = (const float*)d_in[3];
  const float* w_ih   = (const float*)d_in[4];
  const float* w_hh   = (const float*)d_in[5];
  const float* b_ih   = (const float*)d_in[6];
  const float* b_hh   = (const float*)d_in[7];
  const float* w_fc   = (const float*)d_in[8];
  const float* b_fc   = (const float*)d_in[9];
  float* out = (float*)d_out;

  // workspace layout (floats): xw[T*NH] | A[NH] | C[NH] | w2t[NH*NH]
  float* xw  = (float*)d_ws;
  float* Av  = xw + (size_t)T_STEPS * NH;
  float* Cv  = Av + NH;
  float* w2t = Cv + NH;

  // S = e^kappa / (2*pi*I0(kappa)) = sqrt(kappa/(2*pi)) / asymptotic_series
  const double kappa = 1.0 / (0.1745 * 0.1745);
  double series = 1.0, term = 1.0;
  for (int k = 1; k < 16; ++k) {
    term *= ((2.0 * k - 1.0) * (2.0 * k - 1.0)) / (8.0 * kappa * (double)k);
    series += term;
  }
  const float vmS = (float)(sqrt(kappa / (2.0 * PI_D)) / series);

  k0_prep<<<(NH * NH + 255) / 256, 256, 0, stream>>>(w_ih, w_rule, b_rule, b_ih, b_hh,
                                                     Av, Cv, w2t);
  k1_xw<<<T_STEPS / 32, 256, 0, stream>>>(angle, rule, Av, Cv, w2t, xw,
                                          (float)kappa, vmS);
  k2_rnn<<<1, 512, 0, stream>>>(w_hh, xw, out + T_STEPS);
  k3_fc<<<T_STEPS / 4, 256, 0, stream>>>(out + T_STEPS, w_fc, b_fc, out);
}

// Round 8
// 14901.653 us; speedup vs baseline: 1.7449x; 1.6768x over previous
//
#include <hip/hip_runtime.h>
#include <cmath>

#define T_STEPS 16384
#define NH 361
#define NIN 489
#define NRULE 128

typedef _Float16 half8 __attribute__((ext_vector_type(8)));

static constexpr double PI_D = 3.14159265358979323846;

// ---------------------------------------------------------------------------
// k0: one-time prep: transpose W2 = w_ih[:,128:] into w2t[j][i], and fold
//     A[i] = w_ih[i,:128] @ w_rule,  C[i] = w_ih[i,:128] @ b_rule + b_ih + b_hh
// ---------------------------------------------------------------------------
__global__ void k0_prep(const float* __restrict__ w_ih, const float* __restrict__ w_rule,
                        const float* __restrict__ b_rule, const float* __restrict__ b_ih,
                        const float* __restrict__ b_hh,
                        float* __restrict__ Av, float* __restrict__ Cv,
                        float* __restrict__ w2t) {
  int idx = blockIdx.x * 256 + threadIdx.x;
  if (idx < NH * NH) {
    int i = idx % NH;       // output row of w_ih
    int j = idx / NH;       // angle-grid column
    w2t[idx] = w_ih[i * NIN + NRULE + j];   // w2t[j*NH + i]
  }
  if (idx < NH) {
    float a = 0.f, c = 0.f;
    for (int k = 0; k < NRULE; ++k) {
      float w = w_ih[idx * NIN + k];
      a += w * w_rule[k];
      c += w * b_rule[k];
    }
    Av[idx] = a;
    Cv[idx] = c + b_ih[idx] + b_hh[idx];
  }
}

// ---------------------------------------------------------------------------
// k1: xw[t][i] = sum_j w2t[j][i]*vm[t][j] + rule[t]*A[i] + C[i]
// ---------------------------------------------------------------------------
__global__ void k1_xw(const float* __restrict__ angle, const float* __restrict__ rule,
                      const float* __restrict__ Av, const float* __restrict__ Cv,
                      const float* __restrict__ w2t, float* __restrict__ xw,
                      float kappa, float vmS) {
  __shared__ float vm[NH][32];
  __shared__ float srule[32];
  const int tid = threadIdx.x;
  const int t0 = blockIdx.x * 32;
  const float DEG = (float)(PI_D / 180.0);

  for (int idx = tid; idx < NH * 32; idx += 256) {
    int j = idx >> 5;
    int tt = idx & 31;
    float mu = angle[t0 + tt] * DEG;
    float c = __cosf((float)j * DEG - mu);
    vm[j][tt] = vmS * __expf(kappa * (c - 1.f));
  }
  if (tid < 32) srule[tid] = rule[t0 + tid];
  __syncthreads();

  for (int i = tid; i < NH; i += 256) {
    float acc[32];
#pragma unroll
    for (int tt = 0; tt < 32; ++tt) acc[tt] = 0.f;
    for (int j = 0; j < NH; ++j) {
      float wv = w2t[j * NH + i];
#pragma unroll
      for (int tt = 0; tt < 32; ++tt) acc[tt] += wv * vm[j][tt];
    }
    float Ai = Av[i], Ci = Cv[i];
#pragma unroll
    for (int tt = 0; tt < 32; ++tt)
      xw[(t0 + tt) * NH + i] = acc[tt] + srule[tt] * Ai + Ci;
  }
}

// ---------------------------------------------------------------------------
// k2: sequential RNN via v_dot2_f32_f16, geometry sized to FIT the 128-VGPR
//   grant instead of fighting the allocator (R0-R6: every 512/768-thr layout
//   demanded 140-205 regs, got 84-128, and silently spilled the weights ->
//   scratch reload was the true bottleneck all along).
//   1024 threads = 16 waves = 4 waves/EU (the heuristic's natural occupancy).
//   Thread (g = tid>>3, s = tid&7): R=3 rows i = r*128+g, k in [s*48,s*48+48).
//   Weight demand: 3*48 f16 = 72 VGPRs; total ~100 < 128 -> no spill.
//   h chunk: 6 ds_read_b128 reused for 3 rows. S=8 reduce on VALU DPP
//   (xor1, xor2, row_shl:4); after the chain lanes s=0..3 each hold the FULL
//   row sums, so the epilogue is distributed: lane s<3 finishes row r=s
//   (1 row/lane vs 6 serial rows in R4). One barrier/step, double-buffered h.
// ---------------------------------------------------------------------------
__device__ __forceinline__ float dot8(half8 a, half8 b, float acc) {
  acc = __builtin_amdgcn_fdot2(__builtin_shufflevector(a, a, 0, 1),
                               __builtin_shufflevector(b, b, 0, 1), acc, false);
  acc = __builtin_amdgcn_fdot2(__builtin_shufflevector(a, a, 2, 3),
                               __builtin_shufflevector(b, b, 2, 3), acc, false);
  acc = __builtin_amdgcn_fdot2(__builtin_shufflevector(a, a, 4, 5),
                               __builtin_shufflevector(b, b, 4, 5), acc, false);
  acc = __builtin_amdgcn_fdot2(__builtin_shufflevector(a, a, 6, 7),
                               __builtin_shufflevector(b, b, 6, 7), acc, false);
  return acc;
}

template <int CTRL>
__device__ __forceinline__ float dpp_add(float x) {
  int m = __builtin_amdgcn_update_dpp(0, __float_as_int(x), CTRL, 0xF, 0xF, true);
  return x + __int_as_float(m);
}

__global__
__attribute__((amdgpu_flat_work_group_size(1024, 1024), amdgpu_waves_per_eu(4, 4)))
void k2_rnn(const float* __restrict__ w_hh, const float* __restrict__ xw,
            float* __restrict__ hs) {
  __shared__ __align__(16) _Float16 hbuf[2][384];
  const int tid = threadIdx.x;
  const int g = tid >> 3;        // row group 0..127
  const int s = tid & 7;         // k-split 0..7

  // zero both h buffers (h0 = 0; pad rows 361..383 stay 0 forever)
  if (tid < 768) ((_Float16*)hbuf)[tid] = (_Float16)0.f;

  // Weights: rows i = r*128+g (r<3), k in [s*48, s*48+48): 18 half8 = 72 VGPRs
  half8 wt8[18];   // [r*6 + c]
#pragma unroll
  for (int r = 0; r < 3; ++r) {
    const int i = r * 128 + g;
#pragma unroll
    for (int c = 0; c < 6; ++c) {
      half8 v;
#pragma unroll
      for (int e = 0; e < 8; ++e) {
        const int k = s * 48 + c * 8 + e;
        float x = (i < NH && k < NH) ? w_hh[i * NH + k] : 0.f;
        v[e] = (_Float16)x;
      }
      wt8[r * 6 + c] = v;
    }
  }

  // epilogue ownership: lane s<3 of each 8-group finishes row i_own = s*128+g
  const int i_own = s * 128 + g;
  const bool own = (s < 3) && (i_own < NH);
  float xwv = own ? xw[i_own] : 0.f;
  __syncthreads();

  for (int t = 0; t < T_STEPS; ++t) {
    const _Float16* hb = &hbuf[t & 1][s * 48];

    // prefetch next step's xw (owning lanes), hidden under the dot phase
    const int tn = (t + 1 < T_STEPS) ? (t + 1) : t;
    float xwn = own ? xw[(size_t)tn * NH + i_own] : 0.f;

    float ps0 = 0.f, ps1 = 0.f, ps2 = 0.f;
#pragma unroll
    for (int c = 0; c < 6; ++c) {
      half8 h8 = *(const half8*)(hb + c * 8);
      ps0 = dot8(h8, wt8[0 * 6 + c], ps0);
      ps1 = dot8(h8, wt8[1 * 6 + c], ps1);
      ps2 = dot8(h8, wt8[2 * 6 + c], ps2);
    }

    // reduce the 8 k-split partials (VALU DPP). After this chain, lanes
    // s=0..3 of each 8-group all hold the full sum for every row.
    ps0 = dpp_add<0xB1>(ps0);  ps0 = dpp_add<0x4E>(ps0);  ps0 = dpp_add<0x104>(ps0);
    ps1 = dpp_add<0xB1>(ps1);  ps1 = dpp_add<0x4E>(ps1);  ps1 = dpp_add<0x104>(ps1);
    ps2 = dpp_add<0xB1>(ps2);  ps2 = dpp_add<0x4E>(ps2);  ps2 = dpp_add<0x104>(ps2);

    // static select of this lane's row (no runtime-indexed array -> no scratch)
    const float sv0 = (s == 0) ? ps0 : ((s == 1) ? ps1 : ps2);

    if (own) {
      const float sv = sv0 + xwv;
      const float e = __expf(2.f * sv);
      const float h = 1.f - __fdividef(2.f, e + 1.f);
      hs[(size_t)t * NH + i_own] = h;
      hbuf[(t + 1) & 1][i_own] = (_Float16)h;
    }
    xwv = xwn;
    __syncthreads();
  }
}

// ---------------------------------------------------------------------------
// k3: outcome_pre[t] = w_fc . hs[t] + b_fc   (one wave per timestep)
// ---------------------------------------------------------------------------
__global__ void k3_fc(const float* __restrict__ hs, const float* __restrict__ w_fc,
                      const float* __restrict__ b_fc, float* __restrict__ out0) {
  const int t = blockIdx.x * 4 + (threadIdx.x >> 6);
  const int lane = threadIdx.x & 63;
  const float* hrow = hs + (size_t)t * NH;
  float s = 0.f;
  for (int j = lane; j < NH; j += 64) s += w_fc[j] * hrow[j];
#pragma unroll
  for (int off = 32; off > 0; off >>= 1) s += __shfl_down(s, off, 64);
  if (lane == 0) out0[t] = s + b_fc[0];
}

extern "C" void kernel_launch(void* const* d_in, const int* in_sizes, int n_in,
                              void* d_out, int out_size, void* d_ws, size_t ws_size,
                              hipStream_t stream) {
  const float* angle  = (const float*)d_in[0];
  const float* rule   = (const float*)d_in[1];
  const float* w_rule = (const float*)d_in[2];
  const float* b_rule = (const float*)d_in[3];
  const float* w_ih   = (const float*)d_in[4];
  const float* w_hh   = (const float*)d_in[5];
  const float* b_ih   = (const float*)d_in[6];
  const float* b_hh   = (const float*)d_in[7];
  const float* w_fc   = (const float*)d_in[8];
  const float* b_fc   = (const float*)d_in[9];
  float* out = (float*)d_out;

  // workspace layout (floats): xw[T*NH] | A[NH] | C[NH] | w2t[NH*NH]
  float* xw  = (float*)d_ws;
  float* Av  = xw + (size_t)T_STEPS * NH;
  float* Cv  = Av + NH;
  float* w2t = Cv + NH;

  // S = e^kappa / (2*pi*I0(kappa)) = sqrt(kappa/(2*pi)) / asymptotic_series
  const double kappa = 1.0 / (0.1745 * 0.1745);
  double series = 1.0, term = 1.0;
  for (int k = 1; k < 16; ++k) {
    term *= ((2.0 * k - 1.0) * (2.0 * k - 1.0)) / (8.0 * kappa * (double)k);
    series += term;
  }
  const float vmS = (float)(sqrt(kappa / (2.0 * PI_D)) / series);

  k0_prep<<<(NH * NH + 255) / 256, 256, 0, stream>>>(w_ih, w_rule, b_rule, b_ih, b_hh,
                                                     Av, Cv, w2t);
  k1_xw<<<T_STEPS / 32, 256, 0, stream>>>(angle, rule, Av, Cv, w2t, xw,
                                          (float)kappa, vmS);
  k2_rnn<<<1, 1024, 0, stream>>>(w_hh, xw, out + T_STEPS);
  k3_fc<<<T_STEPS / 4, 256, 0, stream>>>(out + T_STEPS, w_fc, b_fc, out);
}